// Round 1
// baseline (642.669 us; speedup 1.0000x reference)
//
#include <hip/hip_runtime.h>

// out[b, d] = sum_k sc[b,k] * dict[serp(d), k]
// B = 262144, K = 32, D = S*S = 900, S = 30.
// Serpentine: for output d = r*30 + c with odd r, source column is r*30 + (29-c).

constexpr int KD    = 32;   // inner dim
constexpr int DDIM  = 900;  // S*S
constexpr int SDIM  = 30;
constexpr int BTILE = 128;  // b-rows per block

__device__ __forceinline__ int serp_src(int d) {
    int r = d / SDIM;          // d < 1024, compiler uses magic-mul
    int c = d - r * SDIM;
    return (r & 1) ? (r * SDIM + (SDIM - 1 - c)) : d;
}

__global__ __launch_bounds__(256, 2) void serp_decode(
    const float* __restrict__ sc,     // [B, 32]
    const float* __restrict__ dict,   // [900, 32]
    float* __restrict__ out,          // [B, 900]
    int B)
{
    const int t  = threadIdx.x;
    const int d1 = blockIdx.x * 256 + t;   // 0..511 (grid.x == 2)
    const int d2 = d1 + 512;               // 512..1023
    const bool v2 = (d2 < DDIM);

    // Pin both dictionary rows (serpentine-remapped) in registers.
    float w1[KD], w2[KD];
    {
        const float4* p = reinterpret_cast<const float4*>(dict + (size_t)serp_src(d1) * KD);
        #pragma unroll
        for (int i = 0; i < KD / 4; ++i) {
            float4 v = p[i];
            w1[4*i+0] = v.x; w1[4*i+1] = v.y; w1[4*i+2] = v.z; w1[4*i+3] = v.w;
        }
        const int s2 = v2 ? serp_src(d2) : 0;   // safe in-bounds addr for masked lanes
        const float4* q = reinterpret_cast<const float4*>(dict + (size_t)s2 * KD);
        #pragma unroll
        for (int i = 0; i < KD / 4; ++i) {
            float4 v = q[i];
            w2[4*i+0] = v.x; w2[4*i+1] = v.y; w2[4*i+2] = v.z; w2[4*i+3] = v.w;
        }
    }

    const int b0 = blockIdx.y * BTILE;
    const float* __restrict__ srow = sc + (size_t)b0 * KD;   // block-uniform address
    float* __restrict__ o1 = out + (size_t)b0 * DDIM + d1;
    float* __restrict__ o2 = o1 + 512;

    const int nb = (B - b0 < BTILE) ? (B - b0) : BTILE;
    for (int bb = 0; bb < nb; ++bb) {
        // Sparse row: same address for every thread in the block -> SMEM/broadcast.
        float s[KD];
        #pragma unroll
        for (int i = 0; i < KD / 4; ++i) {
            float4 v = reinterpret_cast<const float4*>(srow)[i];
            s[4*i+0] = v.x; s[4*i+1] = v.y; s[4*i+2] = v.z; s[4*i+3] = v.w;
        }

        float a1 = 0.f;
        #pragma unroll
        for (int i = 0; i < KD; ++i) a1 = fmaf(s[i], w1[i], a1);
        *o1 = a1;

        if (v2) {   // whole-wave skip for fully-inactive tail waves of block 1
            float a2 = 0.f;
            #pragma unroll
            for (int i = 0; i < KD; ++i) a2 = fmaf(s[i], w2[i], a2);
            *o2 = a2;
        }

        srow += KD;
        o1 += DDIM;
        o2 += DDIM;
    }
}

extern "C" void kernel_launch(void* const* d_in, const int* in_sizes, int n_in,
                              void* d_out, int out_size, void* d_ws, size_t ws_size,
                              hipStream_t stream) {
    const float* sc   = (const float*)d_in[0];   // [B, 32]
    const float* dict = (const float*)d_in[1];   // [900, 32]
    float* out        = (float*)d_out;           // [B, 1, 30, 30] flat = [B, 900]

    const int B = in_sizes[0] / KD;              // 262144

    dim3 grid(2, (unsigned)((B + BTILE - 1) / BTILE));
    serp_decode<<<grid, 256, 0, stream>>>(sc, dict, out, B);
}